// Round 2
// baseline (1102.502 us; speedup 1.0000x reference)
//
#include <hip/hip_runtime.h>
#include <hip/hip_bf16.h>

#define NN 131072      // nodes
#define EE 2097152     // edges
#define FDIM 64
#define NG 256         // graphs
#define TT 8

// ---------- small utility kernels ----------
__global__ __launch_bounds__(256) void k_zero(float* __restrict__ p, int n) {
  int i = blockIdx.x * 256 + threadIdx.x;
  if (i < n) p[i] = 0.f;
}

__global__ __launch_bounds__(256) void k_count(const int* __restrict__ ei, float* __restrict__ cnt) {
  int i = blockIdx.x * 256 + threadIdx.x;
  int stride = gridDim.x * 256;
  for (int e = i; e < EE; e += stride)
    atomicAdd(&cnt[ei[EE + e]], 1.0f);
}

__global__ __launch_bounds__(256) void k_dinv(float* __restrict__ d) {
  int i = blockIdx.x * 256 + threadIdx.x;
  if (i < NN) d[i] = rsqrtf(d[i] + 1.0f);   // deg = dst-count + self-loop, always >= 1
}

// ---------- GEMM: Y[n,c] = sum_k X'[n,k] * W[k,c], X' = relu(X + bias_in) if relu_bias ----------
__global__ __launch_bounds__(256) void k_gemm(const float* __restrict__ X, const float* __restrict__ W,
                                              const float* __restrict__ bias_in, int relu_bias,
                                              float* __restrict__ Y) {
  __shared__ float xs[64 * 64];
  __shared__ float ws[64 * 64];
  int tid = threadIdx.x;
  size_t row0 = (size_t)blockIdx.x * 64;
#pragma unroll
  for (int i = 0; i < 16; ++i) ws[tid + i * 256] = W[tid + i * 256];
#pragma unroll
  for (int i = 0; i < 4; ++i) {
    int idx = tid + i * 256;           // float4 slot in 64x64 tile
    int r = idx >> 4, q = idx & 15;
    float4 v = ((const float4*)(X + (row0 + r) * 64))[q];
    if (relu_bias) {
      int c0 = q * 4;
      v.x = fmaxf(v.x + bias_in[c0 + 0], 0.f);
      v.y = fmaxf(v.y + bias_in[c0 + 1], 0.f);
      v.z = fmaxf(v.z + bias_in[c0 + 2], 0.f);
      v.w = fmaxf(v.w + bias_in[c0 + 3], 0.f);
    }
    *(float4*)&xs[idx * 4] = v;        // idx*4 == r*64 + q*4
  }
  __syncthreads();
  int c = tid & 63, rg = tid >> 6;
  float acc[16];
#pragma unroll
  for (int i = 0; i < 16; ++i) acc[i] = 0.f;
#pragma unroll 4
  for (int kq = 0; kq < 16; ++kq) {
    float w0 = ws[(kq * 4 + 0) * 64 + c];
    float w1 = ws[(kq * 4 + 1) * 64 + c];
    float w2 = ws[(kq * 4 + 2) * 64 + c];
    float w3 = ws[(kq * 4 + 3) * 64 + c];
#pragma unroll
    for (int i = 0; i < 16; ++i) {
      const float4 xv = *(const float4*)&xs[(rg + i * 4) * 64 + kq * 4];
      acc[i] += xv.x * w0 + xv.y * w1 + xv.z * w2 + xv.w * w3;
    }
  }
#pragma unroll
  for (int i = 0; i < 16; ++i)
    Y[(row0 + rg + (size_t)i * 4) * 64 + c] = acc[i];
}

// ---------- self-loop init: agg[i,:] = H[i,:] * dinv[i]^2 ----------
__global__ __launch_bounds__(256) void k_self(const float* __restrict__ H, const float* __restrict__ dinv,
                                              float* __restrict__ agg) {
  int i = blockIdx.x * 256 + threadIdx.x;   // float4 index, total NN*16
  if (i >= NN * 16) return;
  float di = dinv[i >> 4];
  float s = di * di;
  float4 v = ((const float4*)H)[i];
  v.x *= s; v.y *= s; v.z *= s; v.w *= s;
  ((float4*)agg)[i] = v;
}

// ---------- edge scatter: one wave per edge, lane = feature ----------
__global__ __launch_bounds__(256) void k_scatter(const int* __restrict__ ei, const float* __restrict__ H,
                                                 const float* __restrict__ dinv, float* __restrict__ agg) {
  int lane = threadIdx.x & 63;
  int wid = blockIdx.x * 4 + (threadIdx.x >> 6);
  int nw = gridDim.x * 4;
  for (int e = wid; e < EE; e += nw) {
    int s = ei[e];
    int d = ei[EE + e];
    float coef = dinv[s] * dinv[d];
    float v = H[(size_t)s * 64 + lane] * coef;
    atomicAdd(&agg[(size_t)d * 64 + lane], v);
  }
}

// ---------- node blur: z[g,t,f] = sum_rr w[rr]*agg2[g,rr,t,f] + 32*b2[f] ----------
__global__ __launch_bounds__(256) void k_blur(const float* __restrict__ agg2, const float* __restrict__ b2,
                                              float* __restrict__ z) {
  int idx = blockIdx.x * 256 + threadIdx.x;  // NG*TT*FDIM = 131072
  if (idx >= NG * TT * FDIM) return;
  int f = idx & 63, t = (idx >> 6) & 7, g = idx >> 9;
  const float* base = agg2 + ((size_t)g * 512 + (size_t)t) * 64 + f;
  float acc = 0.f;
#pragma unroll
  for (int rr = 0; rr < 64; ++rr) {
    float w = (float)(63 - rr) * (1.0f / 63.0f);
    acc += w * base[(size_t)rr * 8 * 64];
  }
  z[idx] = acc + 32.0f * b2[f];
}

// ---------- classifier head: one block (64 threads) per graph ----------
__global__ __launch_bounds__(64) void k_head(const float* __restrict__ z,
    const float* __restrict__ w1, const float* __restrict__ b1,
    const float* __restrict__ w2, const float* __restrict__ b2,
    const float* __restrict__ w3, const float* __restrict__ b3,
    float* __restrict__ out) {
  __shared__ float zs[512];
  __shared__ float r[64];
  int g = blockIdx.x, c = threadIdx.x;
#pragma unroll
  for (int i = 0; i < 8; ++i) zs[c + i * 64] = z[(size_t)g * 512 + c + i * 64];
  __syncthreads();
  float a = b1[c];
  for (int j = 0; j < 512; ++j) a += zs[j] * w1[j * 64 + c];
  // lif_rate #1
  float mem = 0.f, rate = 0.f;
#pragma unroll
  for (int s = 0; s < 4; ++s) {
    float reset = (mem > 1.0f) ? 1.0f : 0.0f;
    mem = 0.9f * mem + a - reset;
    if (mem - 1.0f > 0.0f) rate += 1.0f;
  }
  r[c] = rate * 0.25f;
  __syncthreads();
  float a2 = b2[c];
#pragma unroll
  for (int j = 0; j < 64; ++j) a2 += r[j] * w2[j * 64 + c];
  __syncthreads();
  // lif_rate #2
  mem = 0.f; rate = 0.f;
#pragma unroll
  for (int s = 0; s < 4; ++s) {
    float reset = (mem > 1.0f) ? 1.0f : 0.0f;
    mem = 0.9f * mem + a2 - reset;
    if (mem - 1.0f > 0.0f) rate += 1.0f;
  }
  r[c] = rate * 0.25f;
  __syncthreads();
  if (c < 10) {
    float o = b3[c];
#pragma unroll
    for (int j = 0; j < 64; ++j) o += r[j] * w3[j * 10 + c];
    out[(size_t)g * 10 + c] = o;
  }
}

extern "C" void kernel_launch(void* const* d_in, const int* in_sizes, int n_in,
                              void* d_out, int out_size, void* d_ws, size_t ws_size,
                              hipStream_t stream) {
  const float* x   = (const float*)d_in[0];
  const int*   ei  = (const int*)d_in[1];
  // d_in[2] = batch (unused: uniform 512-node graphs)
  const float* c1w = (const float*)d_in[3];
  const float* c1b = (const float*)d_in[4];
  const float* c2w = (const float*)d_in[5];
  const float* c2b = (const float*)d_in[6];
  const float* l1w = (const float*)d_in[7];
  const float* l1b = (const float*)d_in[8];
  const float* l2w = (const float*)d_in[9];
  const float* l2b = (const float*)d_in[10];
  const float* l3w = (const float*)d_in[11];
  const float* l3b = (const float*)d_in[12];
  float* out = (float*)d_out;

  char* w = (char*)d_ws;
  float* bufA = (float*)w;                                // 33.5 MB: H1 / H2
  float* bufB = (float*)(w + (size_t)33554432);           // 33.5 MB: agg1 / agg2
  float* dinv = (float*)(w + (size_t)67108864);           // 0.5 MB
  float* z    = (float*)(w + (size_t)67108864 + 524288);  // 0.5 MB

  // degrees -> dinv
  k_zero<<<NN / 256, 256, 0, stream>>>(dinv, NN);
  k_count<<<4096, 256, 0, stream>>>(ei, dinv);
  k_dinv<<<NN / 256, 256, 0, stream>>>(dinv);

  // layer 1: H1 = x @ W1 ; agg1 = selfloop + scatter
  k_gemm<<<NN / 64, 256, 0, stream>>>(x, c1w, nullptr, 0, bufA);
  k_self<<<NN * 16 / 256, 256, 0, stream>>>(bufA, dinv, bufB);
  k_scatter<<<2048, 256, 0, stream>>>(ei, bufA, dinv, bufB);

  // layer 2: H2 = relu(agg1 + b1) @ W2 ; agg2 = selfloop + scatter
  k_gemm<<<NN / 64, 256, 0, stream>>>(bufB, c2w, c1b, 1, bufA);
  k_self<<<NN * 16 / 256, 256, 0, stream>>>(bufA, dinv, bufB);
  k_scatter<<<2048, 256, 0, stream>>>(ei, bufA, dinv, bufB);

  // blur + head
  k_blur<<<NG * TT * FDIM / 256, 256, 0, stream>>>(bufB, c2b, z);
  k_head<<<NG, 64, 0, stream>>>(z, l1w, l1b, l2w, l2b, l3w, l3b, out);
}

// Round 3
// 576.976 us; speedup vs baseline: 1.9108x; 1.9108x over previous
//
#include <hip/hip_runtime.h>
#include <hip/hip_bf16.h>

#define NN 131072      // nodes
#define EE 2097152     // edges
#define NG 256         // graphs
#define TT 8

// ---------- zero (int) ----------
__global__ __launch_bounds__(256) void k_zero_i(int* __restrict__ p, int n) {
  int i = blockIdx.x * 256 + threadIdx.x;
  if (i < n) p[i] = 0;
}

// ---------- degree count by dst (int atomics) ----------
__global__ __launch_bounds__(256) void k_degcnt(const int* __restrict__ ei, int* __restrict__ deg) {
  int e = blockIdx.x * 256 + threadIdx.x;
  if (e < EE) atomicAdd(&deg[ei[EE + e]], 1);
}

// ---------- dinv = rsqrt(deg + 1) ----------
__global__ __launch_bounds__(256) void k_dinv(const int* __restrict__ deg, float* __restrict__ dinv) {
  int i = blockIdx.x * 256 + threadIdx.x;
  if (i < NN) dinv[i] = rsqrtf((float)deg[i] + 1.0f);
}

// ---------- prefix scan (3 stages) for rowptr ----------
__global__ __launch_bounds__(256) void k_scan1(const int* __restrict__ deg, int* __restrict__ rowoff,
                                               int* __restrict__ partials) {
  __shared__ int sm[256];
  int t = threadIdx.x, b = blockIdx.x;
  int v = deg[b * 256 + t];
  sm[t] = v;
  __syncthreads();
  for (int off = 1; off < 256; off <<= 1) {
    int x = (t >= off) ? sm[t - off] : 0;
    __syncthreads();
    sm[t] += x;
    __syncthreads();
  }
  rowoff[b * 256 + t] = sm[t] - v;          // exclusive within block
  if (t == 255) partials[b] = sm[t];        // block total
}

__global__ __launch_bounds__(512) void k_scan2(int* __restrict__ partials) {
  __shared__ int sm[512];
  int t = threadIdx.x;
  int v = partials[t];
  sm[t] = v;
  __syncthreads();
  for (int off = 1; off < 512; off <<= 1) {
    int x = (t >= off) ? sm[t - off] : 0;
    __syncthreads();
    sm[t] += x;
    __syncthreads();
  }
  partials[t] = sm[t] - v;                  // exclusive block offsets
}

__global__ __launch_bounds__(256) void k_scan3(const int* __restrict__ rowoff, const int* __restrict__ partials,
                                               int* __restrict__ rowptr, int* __restrict__ fill) {
  int i = blockIdx.x * 256 + threadIdx.x;
  if (i < NN) { rowptr[i] = rowoff[i] + partials[i >> 8]; fill[i] = 0; }
  if (i == 0) rowptr[NN] = EE;
}

// ---------- CSR fill: col[pos] = src, bucketed by dst ----------
__global__ __launch_bounds__(256) void k_fill(const int* __restrict__ ei, const int* __restrict__ rowptr,
                                              int* __restrict__ fill, int* __restrict__ col) {
  int e = blockIdx.x * 256 + threadIdx.x;
  if (e >= EE) return;
  int s = ei[e], d = ei[EE + e];
  int pos = rowptr[d] + atomicAdd(&fill[d], 1);
  col[pos] = s;
}

// ---------- GEMM: Y[n,c] = sum_k X'[n,k] * W[k,c], X' = relu(X + bias_in) if relu_bias ----------
__global__ __launch_bounds__(256) void k_gemm(const float* __restrict__ X, const float* __restrict__ W,
                                              const float* __restrict__ bias_in, int relu_bias,
                                              float* __restrict__ Y) {
  __shared__ float xs[64 * 64];
  __shared__ float ws[64 * 64];
  int tid = threadIdx.x;
  size_t row0 = (size_t)blockIdx.x * 64;
#pragma unroll
  for (int i = 0; i < 16; ++i) ws[tid + i * 256] = W[tid + i * 256];
#pragma unroll
  for (int i = 0; i < 4; ++i) {
    int idx = tid + i * 256;           // float4 slot in 64x64 tile
    int r = idx >> 4, q = idx & 15;
    float4 v = ((const float4*)(X + (row0 + r) * 64))[q];
    if (relu_bias) {
      int c0 = q * 4;
      v.x = fmaxf(v.x + bias_in[c0 + 0], 0.f);
      v.y = fmaxf(v.y + bias_in[c0 + 1], 0.f);
      v.z = fmaxf(v.z + bias_in[c0 + 2], 0.f);
      v.w = fmaxf(v.w + bias_in[c0 + 3], 0.f);
    }
    *(float4*)&xs[idx * 4] = v;
  }
  __syncthreads();
  int c = tid & 63, rg = tid >> 6;
  float acc[16];
#pragma unroll
  for (int i = 0; i < 16; ++i) acc[i] = 0.f;
#pragma unroll 4
  for (int kq = 0; kq < 16; ++kq) {
    float w0 = ws[(kq * 4 + 0) * 64 + c];
    float w1 = ws[(kq * 4 + 1) * 64 + c];
    float w2 = ws[(kq * 4 + 2) * 64 + c];
    float w3 = ws[(kq * 4 + 3) * 64 + c];
#pragma unroll
    for (int i = 0; i < 16; ++i) {
      const float4 xv = *(const float4*)&xs[(rg + i * 4) * 64 + kq * 4];
      acc[i] += xv.x * w0 + xv.y * w1 + xv.z * w2 + xv.w * w3;
    }
  }
#pragma unroll
  for (int i = 0; i < 16; ++i)
    Y[(row0 + rg + (size_t)i * 4) * 64 + c] = acc[i];
}

// ---------- CSR gather: one wave per dst node, lane = feature ----------
__global__ __launch_bounds__(256) void k_gather(const float* __restrict__ H, const float* __restrict__ dinv,
                                                const int* __restrict__ rowptr, const int* __restrict__ col,
                                                float* __restrict__ agg) {
  int lane = threadIdx.x & 63;
  int node = blockIdx.x * 4 + (threadIdx.x >> 6);
  float di = dinv[node];
  float acc = H[(size_t)node * 64 + lane] * di * di;   // self loop
  int j = rowptr[node], je = rowptr[node + 1];
  for (; j + 1 < je; j += 2) {
    int s0 = col[j], s1 = col[j + 1];
    float c0 = dinv[s0] * di, c1 = dinv[s1] * di;
    float h0 = H[(size_t)s0 * 64 + lane];
    float h1 = H[(size_t)s1 * 64 + lane];
    acc += h0 * c0 + h1 * c1;
  }
  if (j < je) {
    int s0 = col[j];
    acc += H[(size_t)s0 * 64 + lane] * (dinv[s0] * di);
  }
  agg[(size_t)node * 64 + lane] = acc;
}

// ---------- node blur: z[g,t,f] = sum_rr w[rr]*agg2[g,rr,t,f] + 32*b2[f] ----------
__global__ __launch_bounds__(256) void k_blur(const float* __restrict__ agg2, const float* __restrict__ b2,
                                              float* __restrict__ z) {
  int idx = blockIdx.x * 256 + threadIdx.x;  // NG*TT*64 = 131072
  if (idx >= NG * TT * 64) return;
  int f = idx & 63, t = (idx >> 6) & 7, g = idx >> 9;
  const float* base = agg2 + ((size_t)g * 512 + (size_t)t) * 64 + f;
  float acc = 0.f;
#pragma unroll
  for (int rr = 0; rr < 64; ++rr) {
    float w = (float)(63 - rr) * (1.0f / 63.0f);
    acc += w * base[(size_t)rr * 8 * 64];
  }
  z[idx] = acc + 32.0f * b2[f];
}

// ---------- classifier head: one block (64 threads) per graph ----------
__global__ __launch_bounds__(64) void k_head(const float* __restrict__ z,
    const float* __restrict__ w1, const float* __restrict__ b1,
    const float* __restrict__ w2, const float* __restrict__ b2,
    const float* __restrict__ w3, const float* __restrict__ b3,
    float* __restrict__ out) {
  __shared__ float zs[512];
  __shared__ float r[64];
  int g = blockIdx.x, c = threadIdx.x;
#pragma unroll
  for (int i = 0; i < 8; ++i) zs[c + i * 64] = z[(size_t)g * 512 + c + i * 64];
  __syncthreads();
  float a = b1[c];
  for (int j = 0; j < 512; ++j) a += zs[j] * w1[j * 64 + c];
  float mem = 0.f, rate = 0.f;
#pragma unroll
  for (int s = 0; s < 4; ++s) {
    float reset = (mem > 1.0f) ? 1.0f : 0.0f;
    mem = 0.9f * mem + a - reset;
    if (mem - 1.0f > 0.0f) rate += 1.0f;
  }
  r[c] = rate * 0.25f;
  __syncthreads();
  float a2 = b2[c];
#pragma unroll
  for (int j = 0; j < 64; ++j) a2 += r[j] * w2[j * 64 + c];
  __syncthreads();
  mem = 0.f; rate = 0.f;
#pragma unroll
  for (int s = 0; s < 4; ++s) {
    float reset = (mem > 1.0f) ? 1.0f : 0.0f;
    mem = 0.9f * mem + a2 - reset;
    if (mem - 1.0f > 0.0f) rate += 1.0f;
  }
  r[c] = rate * 0.25f;
  __syncthreads();
  if (c < 10) {
    float o = b3[c];
#pragma unroll
    for (int j = 0; j < 64; ++j) o += r[j] * w3[j * 10 + c];
    out[(size_t)g * 10 + c] = o;
  }
}

extern "C" void kernel_launch(void* const* d_in, const int* in_sizes, int n_in,
                              void* d_out, int out_size, void* d_ws, size_t ws_size,
                              hipStream_t stream) {
  const float* x   = (const float*)d_in[0];
  const int*   ei  = (const int*)d_in[1];
  const float* c1w = (const float*)d_in[3];
  const float* c1b = (const float*)d_in[4];
  const float* c2w = (const float*)d_in[5];
  const float* c2b = (const float*)d_in[6];
  const float* l1w = (const float*)d_in[7];
  const float* l1b = (const float*)d_in[8];
  const float* l2w = (const float*)d_in[9];
  const float* l2b = (const float*)d_in[10];
  const float* l3w = (const float*)d_in[11];
  const float* l3b = (const float*)d_in[12];
  float* out = (float*)d_out;

  char* w = (char*)d_ws;
  size_t off = 0;
  float* bufA   = (float*)(w + off); off += (size_t)NN * 64 * 4;   // 32 MB
  float* bufB   = (float*)(w + off); off += (size_t)NN * 64 * 4;   // 32 MB
  float* dinv   = (float*)(w + off); off += (size_t)NN * 4;
  float* z      = (float*)(w + off); off += (size_t)NG * TT * 64 * 4;
  int* rowptr   = (int*)(w + off);   off += ((size_t)NN + 256) * 4;
  int* col      = (int*)(w + off);   off += (size_t)EE * 4;        // 8 MB
  int* deg      = (int*)(w + off);   off += (size_t)NN * 4;
  int* rowoff   = (int*)(w + off);   off += (size_t)NN * 4;
  int* fill     = (int*)(w + off);   off += (size_t)NN * 4;
  int* partials = (int*)(w + off);   off += 4096;

  // CSR build (by dst) + dinv
  k_zero_i<<<NN / 256, 256, 0, stream>>>(deg, NN);
  k_degcnt<<<EE / 256, 256, 0, stream>>>(ei, deg);
  k_dinv<<<NN / 256, 256, 0, stream>>>(deg, dinv);
  k_scan1<<<NN / 256, 256, 0, stream>>>(deg, rowoff, partials);
  k_scan2<<<1, 512, 0, stream>>>(partials);
  k_scan3<<<NN / 256, 256, 0, stream>>>(rowoff, partials, rowptr, fill);
  k_fill<<<EE / 256, 256, 0, stream>>>(ei, rowptr, fill, col);

  // layer 1
  k_gemm<<<NN / 64, 256, 0, stream>>>(x, c1w, nullptr, 0, bufA);
  k_gather<<<NN / 4, 256, 0, stream>>>(bufA, dinv, rowptr, col, bufB);

  // layer 2
  k_gemm<<<NN / 64, 256, 0, stream>>>(bufB, c2w, c1b, 1, bufA);
  k_gather<<<NN / 4, 256, 0, stream>>>(bufA, dinv, rowptr, col, bufB);

  // blur + head
  k_blur<<<NG * TT * 64 / 256, 256, 0, stream>>>(bufB, c2b, z);
  k_head<<<NG, 64, 0, stream>>>(z, l1w, l1b, l2w, l2b, l3w, l3b, out);
}

// Round 4
// 438.230 us; speedup vs baseline: 2.5158x; 1.3166x over previous
//
#include <hip/hip_runtime.h>
#include <hip/hip_bf16.h>

#define NN 131072      // nodes
#define EE 2097152     // edges
#define NG 256         // graphs
#define TT 8

// ---------- zero (int) ----------
__global__ __launch_bounds__(256) void k_zero_i(int* __restrict__ p, int n) {
  int i = blockIdx.x * 256 + threadIdx.x;
  if (i < n) p[i] = 0;
}

// ---------- one-pass ELL build: cnt[d]++ and col[d*maxw+k] = s ----------
__global__ __launch_bounds__(256) void k_fill_ell(const int* __restrict__ ei, int* __restrict__ cnt,
                                                  int* __restrict__ col, int maxw) {
  int e = blockIdx.x * 256 + threadIdx.x;
  if (e >= EE) return;
  int s = ei[e], d = ei[EE + e];
  int k = atomicAdd(&cnt[d], 1);
  if (k < maxw) __builtin_nontemporal_store(s, &col[(size_t)d * maxw + k]);
}

// ---------- GEMM: Y[n,c] = sum_k X'[n,k] * W[k,c], X' = relu(X + bias_in) if relu_bias ----------
__global__ __launch_bounds__(256) void k_gemm(const float* __restrict__ X, const float* __restrict__ W,
                                              const float* __restrict__ bias_in, int relu_bias,
                                              float* __restrict__ Y) {
  __shared__ float xs[64 * 64];
  __shared__ float ws[64 * 64];
  int tid = threadIdx.x;
  size_t row0 = (size_t)blockIdx.x * 64;
#pragma unroll
  for (int i = 0; i < 16; ++i) ws[tid + i * 256] = W[tid + i * 256];
#pragma unroll
  for (int i = 0; i < 4; ++i) {
    int idx = tid + i * 256;           // float4 slot in 64x64 tile
    int r = idx >> 4, q = idx & 15;
    float4 v = ((const float4*)(X + (row0 + r) * 64))[q];
    if (relu_bias) {
      int c0 = q * 4;
      v.x = fmaxf(v.x + bias_in[c0 + 0], 0.f);
      v.y = fmaxf(v.y + bias_in[c0 + 1], 0.f);
      v.z = fmaxf(v.z + bias_in[c0 + 2], 0.f);
      v.w = fmaxf(v.w + bias_in[c0 + 3], 0.f);
    }
    *(float4*)&xs[idx * 4] = v;
  }
  __syncthreads();
  int c = tid & 63, rg = tid >> 6;
  float acc[16];
#pragma unroll
  for (int i = 0; i < 16; ++i) acc[i] = 0.f;
#pragma unroll 4
  for (int kq = 0; kq < 16; ++kq) {
    float w0 = ws[(kq * 4 + 0) * 64 + c];
    float w1 = ws[(kq * 4 + 1) * 64 + c];
    float w2 = ws[(kq * 4 + 2) * 64 + c];
    float w3 = ws[(kq * 4 + 3) * 64 + c];
#pragma unroll
    for (int i = 0; i < 16; ++i) {
      const float4 xv = *(const float4*)&xs[(rg + i * 4) * 64 + kq * 4];
      acc[i] += xv.x * w0 + xv.y * w1 + xv.z * w2 + xv.w * w3;
    }
  }
#pragma unroll
  for (int i = 0; i < 16; ++i)
    Y[(row0 + rg + (size_t)i * 4) * 64 + c] = acc[i];
}

// ---------- ELL gather: one wave per dst node, lane = feature ----------
// dinv computed on the fly from cnt; shfl-broadcast of cooperatively-loaded col row.
__global__ __launch_bounds__(256) void k_gather_ell(const float* __restrict__ H, const int* __restrict__ cnt,
                                                    const int* __restrict__ col, int maxw,
                                                    const int* __restrict__ ei, float* __restrict__ agg) {
  int lane = threadIdx.x & 63;
  int node = blockIdx.x * 4 + (threadIdx.x >> 6);
  int deg = cnt[node];
  float dn = rsqrtf((float)deg + 1.0f);
  float acc = H[(size_t)node * 64 + lane] * (dn * dn);   // self loop
  if (__builtin_expect(deg <= maxw && deg <= 64, 1)) {
    const int* crow = col + (size_t)node * maxw;
    int myc = (lane < deg) ? crow[lane] : 0;
    float mydinv = (lane < deg) ? rsqrtf((float)cnt[myc] + 1.0f) : 0.f;
    int j = 0;
    for (; j + 4 <= deg; j += 4) {
      int s0 = __shfl(myc, j),     s1 = __shfl(myc, j + 1);
      int s2 = __shfl(myc, j + 2), s3 = __shfl(myc, j + 3);
      float c0 = __shfl(mydinv, j),     c1 = __shfl(mydinv, j + 1);
      float c2 = __shfl(mydinv, j + 2), c3 = __shfl(mydinv, j + 3);
      float h0 = H[(size_t)s0 * 64 + lane];
      float h1 = H[(size_t)s1 * 64 + lane];
      float h2 = H[(size_t)s2 * 64 + lane];
      float h3 = H[(size_t)s3 * 64 + lane];
      acc += h0 * (c0 * dn) + h1 * (c1 * dn) + h2 * (c2 * dn) + h3 * (c3 * dn);
    }
    for (; j < deg; ++j) {
      int s0 = __shfl(myc, j);
      float c0 = __shfl(mydinv, j);
      acc += H[(size_t)s0 * 64 + lane] * (c0 * dn);
    }
  } else {
    // exact fallback for ELL overflow (astronomically rare): rescan edge list
    for (int e = 0; e < EE; ++e) {
      if (ei[EE + e] == node) {
        int s = ei[e];
        acc += H[(size_t)s * 64 + lane] * (rsqrtf((float)cnt[s] + 1.0f) * dn);
      }
    }
  }
  agg[(size_t)node * 64 + lane] = acc;
}

// ---------- node blur: z[g,t,f] = sum_rr w[rr]*agg2[g,rr,t,f] + 32*b2[f] ----------
__global__ __launch_bounds__(256) void k_blur(const float* __restrict__ agg2, const float* __restrict__ b2,
                                              float* __restrict__ z) {
  int idx = blockIdx.x * 256 + threadIdx.x;  // NG*TT*64 = 131072
  if (idx >= NG * TT * 64) return;
  int f = idx & 63, t = (idx >> 6) & 7, g = idx >> 9;
  const float* base = agg2 + ((size_t)g * 512 + (size_t)t) * 64 + f;
  float acc = 0.f;
#pragma unroll
  for (int rr = 0; rr < 64; ++rr) {
    float w = (float)(63 - rr) * (1.0f / 63.0f);
    acc += w * base[(size_t)rr * 8 * 64];
  }
  z[idx] = acc + 32.0f * b2[f];
}

// ---------- classifier head: one block (64 threads) per graph ----------
__global__ __launch_bounds__(64) void k_head(const float* __restrict__ z,
    const float* __restrict__ w1, const float* __restrict__ b1,
    const float* __restrict__ w2, const float* __restrict__ b2,
    const float* __restrict__ w3, const float* __restrict__ b3,
    float* __restrict__ out) {
  __shared__ float zs[512];
  __shared__ float r[64];
  int g = blockIdx.x, c = threadIdx.x;
#pragma unroll
  for (int i = 0; i < 8; ++i) zs[c + i * 64] = z[(size_t)g * 512 + c + i * 64];
  __syncthreads();
  float a = b1[c];
  for (int j = 0; j < 512; ++j) a += zs[j] * w1[j * 64 + c];
  float mem = 0.f, rate = 0.f;
#pragma unroll
  for (int s = 0; s < 4; ++s) {
    float reset = (mem > 1.0f) ? 1.0f : 0.0f;
    mem = 0.9f * mem + a - reset;
    if (mem - 1.0f > 0.0f) rate += 1.0f;
  }
  r[c] = rate * 0.25f;
  __syncthreads();
  float a2 = b2[c];
#pragma unroll
  for (int j = 0; j < 64; ++j) a2 += r[j] * w2[j * 64 + c];
  __syncthreads();
  mem = 0.f; rate = 0.f;
#pragma unroll
  for (int s = 0; s < 4; ++s) {
    float reset = (mem > 1.0f) ? 1.0f : 0.0f;
    mem = 0.9f * mem + a2 - reset;
    if (mem - 1.0f > 0.0f) rate += 1.0f;
  }
  r[c] = rate * 0.25f;
  __syncthreads();
  if (c < 10) {
    float o = b3[c];
#pragma unroll
    for (int j = 0; j < 64; ++j) o += r[j] * w3[j * 10 + c];
    out[(size_t)g * 10 + c] = o;
  }
}

extern "C" void kernel_launch(void* const* d_in, const int* in_sizes, int n_in,
                              void* d_out, int out_size, void* d_ws, size_t ws_size,
                              hipStream_t stream) {
  const float* x   = (const float*)d_in[0];
  const int*   ei  = (const int*)d_in[1];
  const float* c1w = (const float*)d_in[3];
  const float* c1b = (const float*)d_in[4];
  const float* c2w = (const float*)d_in[5];
  const float* c2b = (const float*)d_in[6];
  const float* l1w = (const float*)d_in[7];
  const float* l1b = (const float*)d_in[8];
  const float* l2w = (const float*)d_in[9];
  const float* l2b = (const float*)d_in[10];
  const float* l3w = (const float*)d_in[11];
  const float* l3b = (const float*)d_in[12];
  float* out = (float*)d_out;

  char* w = (char*)d_ws;
  size_t off = 0;
  float* bufA = (float*)(w + off); off += (size_t)NN * 64 * 4;   // 32 MB
  float* bufB = (float*)(w + off); off += (size_t)NN * 64 * 4;   // 32 MB
  int* cnt    = (int*)(w + off);   off += (size_t)NN * 4;        // 0.5 MB
  float* z    = (float*)(w + off); off += (size_t)NG * TT * 64 * 4;
  int* col    = (int*)(w + off);
  // runtime ELL width from remaining workspace (<= 64; Poisson(16) max deg ~ 42)
  size_t avail = (ws_size > off) ? (ws_size - off) : 0;
  size_t mw = avail / ((size_t)NN * 4);
  int maxw = (int)(mw < 64 ? mw : 64);
  if (maxw < 1) maxw = 1;   // degenerate; exact fallback path still correct

  k_zero_i<<<NN / 256, 256, 0, stream>>>(cnt, NN);
  k_fill_ell<<<EE / 256, 256, 0, stream>>>(ei, cnt, col, maxw);

  // layer 1
  k_gemm<<<NN / 64, 256, 0, stream>>>(x, c1w, nullptr, 0, bufA);
  k_gather_ell<<<NN / 4, 256, 0, stream>>>(bufA, cnt, col, maxw, ei, bufB);

  // layer 2
  k_gemm<<<NN / 64, 256, 0, stream>>>(bufB, c2w, c1b, 1, bufA);
  k_gather_ell<<<NN / 4, 256, 0, stream>>>(bufA, cnt, col, maxw, ei, bufB);

  // blur + head
  k_blur<<<NG * TT * 64 / 256, 256, 0, stream>>>(bufB, c2b, z);
  k_head<<<NG, 64, 0, stream>>>(z, l1w, l1b, l2w, l2b, l3w, l3b, out);
}